// Round 4
// baseline (192.053 us; speedup 1.0000x reference)
//
#include <hip/hip_runtime.h>
#include <hip/hip_fp16.h>

// RoIAlignRotated on MI355X — R3.
// vs R2: (a) transpose vectorized (float4 reads, half4 writes via LDS tile);
// (b) main kernel output staging split into two bin-phases -> LDS 56.8->32 KB
// -> 4-5 blocks/CU (occupancy was the latency-hiding limiter at 17.6%);
// (c) corner gather = single 8B load (4 fp16 channels).

#define B_ 2
#define C_ 256
#define H_ 200
#define W_ 200
#define OUTHW 7
#define GRID_S 14          // OUTHW * sampling_ratio(2)
#define NSAMP 196          // 14*14
#define ELEMS (C_ * OUTHW * OUTHW)  // 12544

// ---------- NCHW f32 -> NHWC fp16, LDS-tiled, vectorized both sides ----------
__global__ __launch_bounds__(256) void transpose_h_kernel(
    const float* __restrict__ feat, __half* __restrict__ featT)
{
    __shared__ float tile[64][65];   // [c_local][x_local], stride 65
    const int x0 = blockIdx.x * 64;
    const int c0 = blockIdx.y * 64;
    const int yb = blockIdx.z;       // b*H_ + y
    const int y  = yb % H_;
    const int b  = yb / H_;
    const int t  = threadIdx.x;
    const int nx = min(64, W_ - x0);

    // read: thread -> (channel sub-row, float4 along x); wave = 4 rows x 256B
    const int rr = t >> 4;           // 0..15
    const int jj = t & 15;           // float4 index along x
    if (jj * 4 < nx) {
        #pragma unroll
        for (int p = 0; p < 4; ++p) {
            const int cl = p * 16 + rr;
            const float4 v = *(const float4*)(feat +
                ((size_t)(b * C_ + c0 + cl) * H_ + y) * W_ + x0 + jj * 4);
            *(float4*)&tile[cl][jj * 4] = v;   // banks: (cl+4jj)%32, <=2-way
        }
    }
    __syncthreads();

    // write: thread -> (x, channel-quad); 8B half4 stores, 128B contiguous per x
    const int ii = t >> 4;           // x sub-index within pass
    const int cq = (t & 15) * 4;     // channel quad base
    #pragma unroll
    for (int p = 0; p < 4; ++p) {
        const int i = p * 16 + ii;
        if (i < nx) {
            union { __half2 h2[2]; float2 f2; } u;
            u.h2[0] = __floats2half2_rn(tile[cq + 0][i], tile[cq + 1][i]);
            u.h2[1] = __floats2half2_rn(tile[cq + 2][i], tile[cq + 3][i]);
            *(float2*)(featT +
                ((size_t)(b * H_ + y) * W_ + x0 + i) * C_ + c0 + cq) = u.f2;
        }
    }
}

// ---------- per-roi sample table (channel-independent) ----------
__device__ __forceinline__ void build_table(
    const float* __restrict__ rois, int n, int t,
    float s_w[4][NSAMP], int s_idx[4][NSAMP], int pix_stride, int fold_batch,
    int* s_b)
{
    const float spatial_scale = 0.25f;
    if (t == 0 && s_b) *s_b = (int)rois[n * 6 + 0];
    if (t < NSAMP) {
        const int   b  = (int)rois[n * 6 + 0];
        const float cx = rois[n * 6 + 1] * spatial_scale;
        const float cy = rois[n * 6 + 2] * spatial_scale;
        const float rw = fmaxf(rois[n * 6 + 3] * spatial_scale, 1.0f);
        const float rh = fmaxf(rois[n * 6 + 4] * spatial_scale, 1.0f);
        const float th = rois[n * 6 + 5];
        const float cosv = cosf(th), sinv = sinf(th);

        const float bin_h = rh * (1.0f / OUTHW);
        const float bin_w = rw * (1.0f / OUTHW);
        const int row = t / GRID_S;
        const int col = t % GRID_S;

        const float yy = -rh * 0.5f + ((float)row + 0.5f) * 0.5f * bin_h;
        const float xx = -rw * 0.5f + ((float)col + 0.5f) * 0.5f * bin_w;

        const float y = yy * cosv - xx * sinv + cy;
        const float x = yy * sinv + xx * cosv + cx;

        const bool inside = (y >= -1.0f) && (y <= (float)H_) &&
                            (x >= -1.0f) && (x <= (float)W_);

        const float yc = fmaxf(y, 0.0f);
        const float xc = fmaxf(x, 0.0f);
        const float fy = floorf(yc);
        const float fx = floorf(xc);
        int yl = min((int)fy, H_ - 1);
        int xl = min((int)fx, W_ - 1);
        const int yh = min(yl + 1, H_ - 1);
        const int xh = min(xl + 1, W_ - 1);
        const float ly = (fy >= (float)(H_ - 1)) ? 0.0f : (yc - fy);
        const float lx = (fx >= (float)(W_ - 1)) ? 0.0f : (xc - fx);
        const float hy = 1.0f - ly;
        const float hx = 1.0f - lx;

        const float m = inside ? 0.25f : 0.0f;   // fold inside-mask + 2x2 mean
        s_w[0][t] = hy * hx * m;
        s_w[1][t] = hy * lx * m;
        s_w[2][t] = ly * hx * m;
        s_w[3][t] = ly * lx * m;
        const int bb = fold_batch ? b : 0;
        s_idx[0][t] = ((bb * H_ + yl) * W_ + xl) * pix_stride;
        s_idx[1][t] = ((bb * H_ + yl) * W_ + xh) * pix_stride;
        s_idx[2][t] = ((bb * H_ + yh) * W_ + xl) * pix_stride;
        s_idx[3][t] = ((bb * H_ + yh) * W_ + xh) * pix_stride;
    }
}

// ---------- main kernel: two bin-phases to halve LDS ----------
template <int B0, int BC>
__device__ __forceinline__ void roi_phase(
    const __half* __restrict__ featT,
    const float s_w[4][NSAMP], const int s_idx[4][NSAMP],
    float s_out[25][257], float* __restrict__ ob,
    int lane, int wave, int t)
{
    const int cbase = lane * 4;      // 4 channels per lane
    for (int bin = B0 + wave; bin < B0 + BC; bin += 4) {
        const int oy = bin / OUTHW;
        const int ox = bin - oy * OUTHW;
        float a0 = 0.f, a1 = 0.f, a2 = 0.f, a3 = 0.f;
        #pragma unroll
        for (int j = 0; j < 2; ++j) {
            #pragma unroll
            for (int i = 0; i < 2; ++i) {
                const int s = (oy * 2 + j) * GRID_S + (ox * 2 + i);
                #pragma unroll
                for (int q = 0; q < 4; ++q) {
                    const float w = s_w[q][s];
                    const float2 rv =
                        *(const float2*)(featT + s_idx[q][s] + cbase);
                    const __half2* hp = (const __half2*)&rv;
                    const float2 fa = __half22float2(hp[0]);
                    const float2 fb = __half22float2(hp[1]);
                    a0 += w * fa.x; a1 += w * fa.y;
                    a2 += w * fb.x; a3 += w * fb.y;
                }
            }
        }
        const int jb = bin - B0;
        s_out[jb][0 * 64 + lane] = a0;   // swizzled: c=cbase+k at col k*64+lane
        s_out[jb][1 * 64 + lane] = a1;
        s_out[jb][2 * 64 + lane] = a2;
        s_out[jb][3 * 64 + lane] = a3;
    }
    __syncthreads();
    // drain: contiguous-ish stores; phase-split partial lines merge in L2
    #pragma unroll 4
    for (int m = t; m < BC * 256; m += 256) {
        const int c = m / BC;
        const int j = m - c * BC;
        ob[c * 49 + B0 + j] = s_out[j][(c & 3) * 64 + (c >> 2)];
    }
}

__global__ __launch_bounds__(256) void roi_main_nhwc_h(
    const __half* __restrict__ featT,
    const float* __restrict__ rois,
    float* __restrict__ out)
{
    __shared__ float s_w[4][NSAMP];
    __shared__ int   s_idx[4][NSAMP];
    __shared__ float s_out[25][257];   // ~25.7 KB; total LDS ~31.9 KB

    const int n = blockIdx.x;
    const int t = threadIdx.x;
    build_table(rois, n, t, s_w, s_idx, C_, 1, nullptr);
    __syncthreads();

    const int lane = t & 63;
    const int wave = t >> 6;
    float* __restrict__ ob = out + (size_t)n * ELEMS;

    roi_phase<0, 25>(featT, s_w, s_idx, s_out, ob, lane, wave, t);
    __syncthreads();   // drain-A reads done before phase-B overwrites s_out
    roi_phase<25, 24>(featT, s_w, s_idx, s_out, ob, lane, wave, t);
}

// ---------- fallback (known-correct NCHW path, no workspace) ----------
__global__ __launch_bounds__(256) void roi_main_nchw(
    const float* __restrict__ feat,
    const float* __restrict__ rois,
    float* __restrict__ out)
{
    const int n = blockIdx.x;
    const int t = threadIdx.x;
    __shared__ float s_w[4][NSAMP];
    __shared__ int   s_idx[4][NSAMP];
    __shared__ int   s_b;

    build_table(rois, n, t, s_w, s_idx, 1, 0, &s_b);
    __syncthreads();

    const float* __restrict__ fb = feat + (size_t)s_b * (size_t)(C_ * H_ * W_);
    float* __restrict__ ob = out + (size_t)n * (size_t)ELEMS;

    for (int e = t; e < ELEMS; e += 256) {
        const int c   = e / 49;
        const int bin = e - c * 49;
        const int oy  = bin / 7;
        const int ox  = bin - oy * 7;
        const float* __restrict__ fc = fb + c * (H_ * W_);
        float acc = 0.0f;
        #pragma unroll
        for (int j = 0; j < 2; ++j) {
            #pragma unroll
            for (int i = 0; i < 2; ++i) {
                const int s = (oy * 2 + j) * GRID_S + (ox * 2 + i);
                acc += s_w[0][s] * fc[s_idx[0][s]];
                acc += s_w[1][s] * fc[s_idx[1][s]];
                acc += s_w[2][s] * fc[s_idx[2][s]];
                acc += s_w[3][s] * fc[s_idx[3][s]];
            }
        }
        ob[e] = acc;
    }
}

extern "C" void kernel_launch(void* const* d_in, const int* in_sizes, int n_in,
                              void* d_out, int out_size, void* d_ws, size_t ws_size,
                              hipStream_t stream) {
    const float* feat = (const float*)d_in[0];
    const float* rois = (const float*)d_in[1];
    float* out = (float*)d_out;
    const int N = in_sizes[1] / 6;  // 1000

    const size_t need = (size_t)B_ * H_ * W_ * C_ * sizeof(__half); // 41 MB
    if (ws_size >= need) {
        __half* featT = (__half*)d_ws;
        dim3 tg((W_ + 63) / 64, C_ / 64, H_ * B_);
        transpose_h_kernel<<<tg, 256, 0, stream>>>(feat, featT);
        roi_main_nhwc_h<<<N, 256, 0, stream>>>(featT, rois, out);
    } else {
        roi_main_nchw<<<N, 256, 0, stream>>>(feat, rois, out);
    }
}